// Round 3
// baseline (370.890 us; speedup 1.0000x reference)
//
#include <hip/hip_runtime.h>
#include <stdint.h>

// Problem constants (from reference)
#define BATCH   2048
#define IN_BITS 4096
#define N_IN    2048
#define N_ST    1024
#define N_OUT   1024
#define KBITS   14
#define MW      512    // 2^14 bits / 32 = words per packed mem row

// Unified bit-row layout for layer inputs: [B][128 words]
//   words 0..63   : h_in   (2048 bits)  -- written by layer 1
//   words 64..95  : state  (1024 bits)  -- written by pack_st
//   words 96..127 : s_out  (1024 bits)  -- written by layer 2
#define BROW 128
#define PAD  129   // LDS padded stride (odd -> bank (lane+wd)&31, 2-way free)

// float/int element counts
#define IM_F 33554432L   // N_IN * 16384
#define SM_F 16777216L
#define OM_F 16777216L

// ---------------------------------------------------------------------------
// Ballot-based packing: wave handles 1024 consecutive elements.
// Lane l loads element j*64+l (fully coalesced 256B/instr, 16 independent
// loads in flight); ballot(v==TRUE) IS the packed 64-bit word. Lane 0 stores
// 8 x uint4 (128B contiguous).
__global__ __launch_bounds__(256) void pack_mem(const float* __restrict__ im,
                                                const float* __restrict__ sm,
                                                const float* __restrict__ om,
                                                uint32_t* __restrict__ dst) {
    int wid = (blockIdx.x * 256 + threadIdx.x) >> 6;
    int lane = threadIdx.x & 63;
    long f0 = (long)wid << 10;
    const float* s;
    long base;
    if (f0 < IM_F)              { s = im; base = f0; }
    else if (f0 < IM_F + SM_F)  { s = sm; base = f0 - IM_F; }
    else                        { s = om; base = f0 - (IM_F + SM_F); }
    unsigned long long m[16];
#pragma unroll
    for (int j = 0; j < 16; j++)
        m[j] = __ballot(s[base + j * 64 + lane] == 1.0f);
    if (lane == 0) {
        uint4* o = (uint4*)(dst + (f0 >> 5));
#pragma unroll
        for (int j = 0; j < 8; j++) {
            uint4 q;
            q.x = (uint32_t)m[2 * j];
            q.y = (uint32_t)(m[2 * j] >> 32);
            q.z = (uint32_t)m[2 * j + 1];
            q.w = (uint32_t)(m[2 * j + 1] >> 32);
            o[j] = q;
        }
    }
}

__global__ __launch_bounds__(256) void pack_in(const int* __restrict__ src,
                                               uint32_t* __restrict__ dst) {
    int wid = (blockIdx.x * 256 + threadIdx.x) >> 6;
    int lane = threadIdx.x & 63;
    long f0 = (long)wid << 10;
    unsigned long long m[16];
#pragma unroll
    for (int j = 0; j < 16; j++)
        m[j] = __ballot(src[f0 + j * 64 + lane] == 1);
    if (lane == 0) {
        uint4* o = (uint4*)(dst + (f0 >> 5));
#pragma unroll
        for (int j = 0; j < 8; j++) {
            uint4 q;
            q.x = (uint32_t)m[2 * j];
            q.y = (uint32_t)(m[2 * j] >> 32);
            q.z = (uint32_t)m[2 * j + 1];
            q.w = (uint32_t)(m[2 * j + 1] >> 32);
            o[j] = q;
        }
    }
}

// state_bits: one wave per batch row (1024 bits); dst words 64..95 of buf row.
__global__ __launch_bounds__(256) void pack_st(const int* __restrict__ src,
                                               uint32_t* __restrict__ buf) {
    int wid = (blockIdx.x * 256 + threadIdx.x) >> 6;
    int lane = threadIdx.x & 63;
    long f0 = (long)wid << 10;
    unsigned long long m[16];
#pragma unroll
    for (int j = 0; j < 16; j++)
        m[j] = __ballot(src[f0 + j * 64 + lane] == 1);
    if (lane == 0) {
        uint4* o = (uint4*)(buf + (long)wid * BROW + 64);
#pragma unroll
        for (int j = 0; j < 8; j++) {
            uint4 q;
            q.x = (uint32_t)m[2 * j];
            q.y = (uint32_t)(m[2 * j] >> 32);
            q.z = (uint32_t)m[2 * j + 1];
            q.w = (uint32_t)(m[2 * j + 1] >> 32);
            o[j] = q;
        }
    }
}

// ---------------------------------------------------------------------------
// RAM layer, lane = batch row. Block: 64 batch rows staged in LDS (padded
// stride 129 -> the uniform-offset reads hit banks (lane+wd)&31 = conflict-
// free 2-way). Each wave handles NW consecutive neurons: conn is scalar
// (s_load), 14 LDS bit-extracts build the 14-bit address (k=0 is MSB), one
// 4B gather lands inside the neuron's 2KB packed mem row (<=32 lines, L1/L2
// resident). ballot over batch -> lane i keeps neuron i's column; after the
// NW loop a 6-step shfl_xor 64x64 bit transpose gives lane b the neuron bits
// for batch row b0+b.
// MODE 0: u32 store to buf words 0..63   (h_in,  NW=32)
// MODE 1: u16 store to buf words 96..127 (s_out, NW=16)
// MODE 2: u16 store to pout [B][32]      (out,   NW=16; conn idx>=2048 -> +32 words)
template <int NW, int MODE>
__global__ __launch_bounds__(256) void ram_layer(const uint32_t* __restrict__ src,
                                                 const int* __restrict__ conn,
                                                 const uint32_t* __restrict__ memp,
                                                 uint32_t* __restrict__ dst) {
    __shared__ uint32_t lds[64 * PAD];
    const int tid = threadIdx.x;
    const int b0 = blockIdx.y * 64;

    // Stage 64 rows x 128 words (coalesced uint4 reads, b32 LDS writes).
    {
        const uint4* g = (const uint4*)(src + (long)b0 * BROW);
        for (int v = tid; v < 64 * BROW / 4; v += 256) {
            uint4 d = g[v];
            int row = v >> 5;            // 32 uint4 per row
            int col = (v & 31) * 4;
            uint32_t* p = lds + row * PAD + col;
            p[0] = d.x; p[1] = d.y; p[2] = d.z; p[3] = d.w;
        }
    }
    __syncthreads();

    const int lane = tid & 63;
    const int wv = __builtin_amdgcn_readfirstlane(tid >> 6);
    const int n0 = blockIdx.x * (4 * NW) + wv * NW;
    const uint32_t* myrow = lds + lane * PAD;

    unsigned long long msk = 0;
#pragma unroll 2
    for (int i = 0; i < NW; ++i) {
        const int n = n0 + i;                    // wave-uniform -> s_loads
        const int* c = conn + n * KBITS;
        uint32_t addr = 0;
#pragma unroll
        for (int k = 0; k < KBITS; k++) {
            int idx = c[k];
            int wd = idx >> 5;
            if (MODE == 2 && idx >= 2048) wd += 32;   // skip state region
            addr = (addr << 1) | ((myrow[wd] >> (idx & 31)) & 1u);
        }
        uint32_t v = memp[(long)n * MW + (addr >> 5)];
        unsigned long long m = __ballot(((v >> (addr & 31)) & 1u) != 0);
        msk = (lane == i) ? m : msk;
    }

    // 64x64 bit transpose across lanes (block-swap algorithm).
    unsigned long long x = msk;
#define TSTEP(S, M)                                                         \
    {                                                                       \
        unsigned long long t =                                              \
            (unsigned long long)__shfl_xor((long long)x, S, 64);            \
        x = (lane & S) ? ((x & ~(M)) | ((t & ~(M)) >> S))                   \
                       : ((x & (M)) | ((t & (M)) << S));                    \
    }
    TSTEP(32, 0x00000000ffffffffULL)
    TSTEP(16, 0x0000ffff0000ffffULL)
    TSTEP(8,  0x00ff00ff00ff00ffULL)
    TSTEP(4,  0x0f0f0f0f0f0f0f0fULL)
    TSTEP(2,  0x3333333333333333ULL)
    TSTEP(1,  0x5555555555555555ULL)
#undef TSTEP

    // lane b now holds bits for neurons n0..n0+NW-1 of batch row b0+b.
    if (MODE == 0) {
        *(uint32_t*)(dst + (long)(b0 + lane) * BROW + (n0 >> 5)) = (uint32_t)x;
    } else if (MODE == 1) {
        ((uint16_t*)(dst + (long)(b0 + lane) * BROW + 96))[n0 >> 4] = (uint16_t)x;
    } else {
        ((uint16_t*)(dst + (long)(b0 + lane) * 32))[n0 >> 4] = (uint16_t)x;
    }
}

// ---------------------------------------------------------------------------
// Expand packed output bits to floats. Thread -> 4 floats (float4 store).
__global__ __launch_bounds__(256) void expand_out(const uint32_t* __restrict__ pout,
                                                  float4* __restrict__ out) {
    int t = blockIdx.x * 256 + threadIdx.x;
    int b = t >> 8;                 // 256 threads per batch row (1024 floats)
    int c4 = (t & 255) * 4;
    uint32_t w = pout[b * 32 + (c4 >> 5)];
    int sh = c4 & 31;
    float4 f;
    f.x = (float)((w >> (sh + 0)) & 1u);
    f.y = (float)((w >> (sh + 1)) & 1u);
    f.z = (float)((w >> (sh + 2)) & 1u);
    f.w = (float)((w >> (sh + 3)) & 1u);
    out[t] = f;
}

// ---------------------------------------------------------------------------
extern "C" void kernel_launch(void* const* d_in, const int* in_sizes, int n_in,
                              void* d_out, int out_size, void* d_ws, size_t ws_size,
                              hipStream_t stream) {
    const int*   input_bits = (const int*)d_in[0];
    const int*   state_bits = (const int*)d_in[1];
    const int*   in_conn    = (const int*)d_in[2];
    const float* in_mem     = (const float*)d_in[3];
    const int*   st_conn    = (const int*)d_in[4];
    const float* st_mem     = (const float*)d_in[5];
    const int*   out_conn   = (const int*)d_in[6];
    const float* out_mem    = (const float*)d_in[7];
    float*       out        = (float*)d_out;

    // Workspace layout:
    //   bits1 @ 0        : [B][128] u32 = 1 MB   (packed input_bits)
    //   buf   @ 1 MB     : [B][128] u32 = 1 MB   (h_in | state | s_out)
    //   pout  @ 2 MB     : [B][32]  u32 = 256 KB (packed output bits)
    //   tbl   @ 2.25 MB  : im_p 4 MB | sm_p 2 MB | om_p 2 MB (contiguous)
    char* ws = (char*)d_ws;
    uint32_t* bits1 = (uint32_t*)(ws);
    uint32_t* buf   = (uint32_t*)(ws + 1048576);
    uint32_t* pout  = (uint32_t*)(ws + 2097152);
    uint32_t* tbl   = (uint32_t*)(ws + 2359296);
    uint32_t* im_p  = tbl;
    uint32_t* sm_p  = tbl + 1048576;   // +4 MB in words
    uint32_t* om_p  = tbl + 1572864;   // +6 MB in words

    // Bit-pack (ballot-based, coalesced, 16 loads in flight per wave).
    pack_in<<<2048, 256, 0, stream>>>(input_bits, bits1);
    pack_st<<<512, 256, 0, stream>>>(state_bits, buf);
    pack_mem<<<16384, 256, 0, stream>>>(in_mem, st_mem, out_mem, tbl);

    // Layer 1: bits1 -> h_in (buf words 0..63)
    ram_layer<32, 0><<<dim3(16, 32), 256, 0, stream>>>(bits1, in_conn, im_p, buf);
    // Layer 2: buf(h_in|state) -> s_out (buf words 96..127)
    ram_layer<16, 1><<<dim3(16, 32), 256, 0, stream>>>(buf, st_conn, sm_p, buf);
    // Layer 3: buf(h_in|s_out) -> packed out bits
    ram_layer<16, 2><<<dim3(16, 32), 256, 0, stream>>>(buf, out_conn, om_p, pout);

    // Expand packed bits -> float output.
    expand_out<<<2048, 256, 0, stream>>>(pout, (float4*)out);
}

// Round 4
// 350.474 us; speedup vs baseline: 1.0583x; 1.0583x over previous
//
#include <hip/hip_runtime.h>
#include <stdint.h>

// Problem constants
#define BATCH   2048
#define KBITS   14
#define MW      512    // 2^14 bits / 32 words per packed mem row
#define BROW    128    // unified bit-row: h_in[0..63] | state[64..95] | s_out[96..127]
#define PAD     129    // LDS padded stride: bank=(lane+wd)&31 -> 2-way (free)

#define IM_F 33554432L   // N_IN * 16384 floats
#define SM_F 16777216L

// pack_all wave-section boundaries (each wave packs 2048 elements = 8 KB)
#define W_IN  4096   // input_bits : 8,388,608 ints
#define W_ST  5120   // state_bits : 2,097,152 ints
#define W_END 37888  // mem floats : 67,108,864

// ---------------------------------------------------------------------------
// One kernel packs everything. Per wave: 2048 consecutive elements as
// 8 independent 16B loads per lane (lane-contiguous per instr -> 1KB/instr,
// 128B in flight per lane). nibble -> 3-step shfl_xor assembles each 32-bit
// word in lanes l%8==0; stores are 32B contiguous per instr.
__global__ __launch_bounds__(256) void pack_all(
    const int4* __restrict__ in_b, const int4* __restrict__ st_b,
    const float4* __restrict__ im, const float4* __restrict__ sm,
    const float4* __restrict__ om,
    uint32_t* __restrict__ bits1, uint32_t* __restrict__ buf,
    uint32_t* __restrict__ tbl) {
    const int gw = (blockIdx.x * 256 + threadIdx.x) >> 6;
    const int lane = threadIdx.x & 63;
    uint32_t nib[8];
    long wbase;
    if (gw < W_ST) {
        const int4* src;
        long ebase;
        if (gw < W_IN) { src = in_b; ebase = (long)gw << 11; }
        else           { src = st_b; ebase = (long)(gw - W_IN) << 11; }
        const int4* p = src + (ebase >> 2) + lane;
        int4 r[8];
#pragma unroll
        for (int j = 0; j < 8; j++) r[j] = p[j * 64];
#pragma unroll
        for (int j = 0; j < 8; j++)
            nib[j] = (uint32_t)(r[j].x == 1) | ((uint32_t)(r[j].y == 1) << 1) |
                     ((uint32_t)(r[j].z == 1) << 2) | ((uint32_t)(r[j].w == 1) << 3);
        wbase = ebase >> 5;
    } else {
        long fbase = (long)(gw - W_ST) << 11;
        const float4* src;
        long eb;
        if (fbase < IM_F)             { src = im; eb = fbase; }
        else if (fbase < IM_F + SM_F) { src = sm; eb = fbase - IM_F; }
        else                          { src = om; eb = fbase - IM_F - SM_F; }
        const float4* p = src + (eb >> 2) + lane;
        float4 r[8];
#pragma unroll
        for (int j = 0; j < 8; j++) r[j] = p[j * 64];
#pragma unroll
        for (int j = 0; j < 8; j++)
            nib[j] = (uint32_t)(r[j].x == 1.0f) | ((uint32_t)(r[j].y == 1.0f) << 1) |
                     ((uint32_t)(r[j].z == 1.0f) << 2) | ((uint32_t)(r[j].w == 1.0f) << 3);
        wbase = fbase >> 5;
    }
    uint32_t w[8];
#pragma unroll
    for (int j = 0; j < 8; j++) {
        uint32_t x = nib[j] << (4 * (lane & 7));
        x |= __shfl_xor(x, 1, 64);
        x |= __shfl_xor(x, 2, 64);
        x |= __shfl_xor(x, 4, 64);
        w[j] = x;
    }
    if ((lane & 7) == 0) {
        const int s = lane >> 3;
        if (gw < W_IN) {
#pragma unroll
            for (int j = 0; j < 8; j++) bits1[wbase + j * 8 + s] = w[j];
        } else if (gw < W_ST) {
#pragma unroll
            for (int j = 0; j < 8; j++) {
                long g = wbase + j * 8 + s;             // state word idx; 32/row
                buf[(g >> 5) * BROW + 64 + (g & 31)] = w[j];
            }
        } else {
#pragma unroll
            for (int j = 0; j < 8; j++) tbl[wbase + j * 8 + s] = w[j];
        }
    }
}

// ---------------------------------------------------------------------------
// RAM layer, lane = batch row; 64 rows staged in LDS (stride 129 -> 2-way
// free). Wave handles NW consecutive neurons: conn is wave-uniform (s_load),
// 14 LDS bit-extracts -> 14-bit address (k=0 MSB), one 4B gather inside the
// neuron's 2KB packed row (L1/L2 resident). ballot over batch -> transpose.
// MODE 0: u16 store to buf words 0..63   (h_in,  NW=16)
// MODE 1: u8  store to buf words 96..127 (s_out, NW=8)
// MODE 2: float output direct            (out,   NW=8; idx>=2048 -> +32 words)
template <int NW, int MODE>
__global__ __launch_bounds__(256) void ram_layer(const uint32_t* __restrict__ src,
                                                 const int* __restrict__ conn,
                                                 const uint32_t* __restrict__ memp,
                                                 uint32_t* __restrict__ dst,
                                                 float* __restrict__ fout) {
    __shared__ uint32_t lds[64 * PAD];
    const int tid = threadIdx.x;
    const int b0 = blockIdx.y * 64;
    {
        const uint4* g = (const uint4*)(src + (long)b0 * BROW);
        for (int v = tid; v < 64 * BROW / 4; v += 256) {
            uint4 d = g[v];
            int row = v >> 5;
            int col = (v & 31) * 4;
            uint32_t* p = lds + row * PAD + col;
            p[0] = d.x; p[1] = d.y; p[2] = d.z; p[3] = d.w;
        }
    }
    __syncthreads();

    const int lane = tid & 63;
    const int wv = __builtin_amdgcn_readfirstlane(tid >> 6);
    const int n0 = blockIdx.x * (4 * NW) + wv * NW;
    const uint32_t* myrow = lds + lane * PAD;

    unsigned long long msk = 0;
#pragma unroll 2
    for (int i = 0; i < NW; ++i) {
        const int n = n0 + i;
        const int* c = conn + n * KBITS;
        uint32_t addr = 0;
#pragma unroll
        for (int k = 0; k < KBITS; k++) {
            int idx = c[k];
            int wd = idx >> 5;
            if (MODE == 2 && idx >= 2048) wd += 32;   // o_inp: skip state region
            addr = (addr << 1) | ((myrow[wd] >> (idx & 31)) & 1u);
        }
        uint32_t v = memp[(long)n * MW + (addr >> 5)];
        unsigned long long m = __ballot(((v >> (addr & 31)) & 1u) != 0);
        msk = (lane == i) ? m : msk;
    }

    // 64x64 bit transpose across lanes.
    unsigned long long x = msk;
#define TSTEP(S, M)                                                         \
    {                                                                       \
        unsigned long long t =                                              \
            (unsigned long long)__shfl_xor((long long)x, S, 64);            \
        x = (lane & S) ? ((x & ~(M)) | ((t & ~(M)) >> S))                   \
                       : ((x & (M)) | ((t & (M)) << S));                    \
    }
    TSTEP(32, 0x00000000ffffffffULL)
    TSTEP(16, 0x0000ffff0000ffffULL)
    TSTEP(8,  0x00ff00ff00ff00ffULL)
    TSTEP(4,  0x0f0f0f0f0f0f0f0fULL)
    TSTEP(2,  0x3333333333333333ULL)
    TSTEP(1,  0x5555555555555555ULL)
#undef TSTEP

    // lane b holds bits for neurons n0..n0+NW-1 of batch row b0+b.
    if (MODE == 0) {
        ((uint16_t*)(dst + (long)(b0 + lane) * BROW))[n0 >> 4] = (uint16_t)x;
    } else if (MODE == 1) {
        ((uint8_t*)(dst + (long)(b0 + lane) * BROW + 96))[n0 >> 3] = (uint8_t)x;
    } else {
        float* o = fout + (long)(b0 + lane) * 1024 + n0;
        float4 f0, f1;
        f0.x = (float)((x >> 0) & 1); f0.y = (float)((x >> 1) & 1);
        f0.z = (float)((x >> 2) & 1); f0.w = (float)((x >> 3) & 1);
        f1.x = (float)((x >> 4) & 1); f1.y = (float)((x >> 5) & 1);
        f1.z = (float)((x >> 6) & 1); f1.w = (float)((x >> 7) & 1);
        ((float4*)o)[0] = f0;
        ((float4*)o)[1] = f1;
    }
}

// ---------------------------------------------------------------------------
extern "C" void kernel_launch(void* const* d_in, const int* in_sizes, int n_in,
                              void* d_out, int out_size, void* d_ws, size_t ws_size,
                              hipStream_t stream) {
    const int*   input_bits = (const int*)d_in[0];
    const int*   state_bits = (const int*)d_in[1];
    const int*   in_conn    = (const int*)d_in[2];
    const float* in_mem     = (const float*)d_in[3];
    const int*   st_conn    = (const int*)d_in[4];
    const float* st_mem     = (const float*)d_in[5];
    const int*   out_conn   = (const int*)d_in[6];
    const float* out_mem    = (const float*)d_in[7];
    float*       out        = (float*)d_out;

    // Workspace: bits1 [B][128] @0 (1MB) | buf [B][128] @1MB (1MB) |
    //            tbl @2MB: im_p 4MB | sm_p 2MB | om_p 2MB
    char* ws = (char*)d_ws;
    uint32_t* bits1 = (uint32_t*)(ws);
    uint32_t* buf   = (uint32_t*)(ws + 1048576);
    uint32_t* tbl   = (uint32_t*)(ws + 2097152);
    uint32_t* im_p  = tbl;
    uint32_t* sm_p  = tbl + 1048576;
    uint32_t* om_p  = tbl + 1572864;

    pack_all<<<W_END / 4, 256, 0, stream>>>(
        (const int4*)input_bits, (const int4*)state_bits,
        (const float4*)in_mem, (const float4*)st_mem, (const float4*)out_mem,
        bits1, buf, tbl);

    // Layer 1: bits1 -> h_in (buf words 0..63)
    ram_layer<16, 0><<<dim3(32, 32), 256, 0, stream>>>(bits1, in_conn, im_p, buf, nullptr);
    // Layer 2: buf(h_in|state) -> s_out (buf words 96..127)
    ram_layer<8, 1><<<dim3(32, 32), 256, 0, stream>>>(buf, st_conn, sm_p, buf, nullptr);
    // Layer 3: buf(h_in|s_out) -> float output
    ram_layer<8, 2><<<dim3(32, 32), 256, 0, stream>>>(buf, out_conn, om_p, nullptr, out);
}